// Round 12
// baseline (78.765 us; speedup 1.0000x reference)
//
#include <hip/hip_runtime.h>
#include <hip/hip_bf16.h>

#define H_ 256
#define W_ 256
#define C_ 128
#define NBPOS 1024   // N * 16 * 16 block positions
#define NACT 512

typedef __bf16 bf16x8 __attribute__((ext_vector_type(8)));
typedef float f32x4 __attribute__((ext_vector_type(4)));

// workspace layout (bytes)
#define SCALE_OFF 294912
#define SHIFT_OFF 295424
#define INACT_OFF 295936

// LDS-visibility barrier that does NOT drain vmcnt: in-flight global loads
// (weight prefetch + embedded copy stream) ride across it. R11-validated.
#define LGKM_BARRIER() do { \
  asm volatile("s_waitcnt lgkmcnt(0)" ::: "memory"); \
  __builtin_amdgcn_s_barrier(); \
  __builtin_amdgcn_sched_barrier(0); \
} while (0)

// Blocks 0..575: weight repack fp32 HWIO -> bf16 [tap][cin8][cout][8].
// Block 576: BN fold + inactive-block list (bitmap + compaction).
__global__ void prep_kernel(const float* __restrict__ w, const float* __restrict__ b,
                            const float* __restrict__ gamma, const float* __restrict__ beta,
                            const float* __restrict__ mean, const float* __restrict__ var,
                            const int* __restrict__ active,
                            __bf16* __restrict__ wprep, float* __restrict__ scale,
                            float* __restrict__ shift, int* __restrict__ inact) {
  int blk = blockIdx.x, tid = threadIdx.x;
  if (blk < 576) {
    int o = blk * 256 + tid;
    int j = o & 7, cout = (o >> 3) & 127, k8 = (o >> 10) & 15, tap = o >> 14;
    wprep[o] = (__bf16)w[((size_t)tap * 128 + k8 * 8 + j) * 128 + cout];
    return;
  }
  __shared__ unsigned mask[32];
  __shared__ int cnt;
  if (tid < 32) mask[tid] = 0u;
  if (tid == 0) cnt = 0;
  __syncthreads();
  for (int i = tid; i < NACT; i += 256) {
    int a = active[i];
    atomicOr(&mask[a >> 5], 1u << (a & 31));
  }
  if (tid < 128) {
    float s = gamma[tid] * rsqrtf(var[tid] + 1e-3f);
    scale[tid] = s;
    shift[tid] = (b[tid] - mean[tid]) * s + beta[tid];
  }
  __syncthreads();
  for (int p = tid; p < NBPOS; p += 256) {
    if (!((mask[p >> 5] >> (p & 31)) & 1u)) {
      int q = atomicAdd(&cnt, 1);
      inact[q] = p;   // order nondeterministic; disjoint coverage is what matters
    }
  }
}

// 512 wgs, one per active block (exactly 2 wg/CU at 57.9 KB LDS). Each wg:
//  - conv of active[i]: full 16x16 block, M=256 x N=128 x K=1152 implicit GEMM,
//    wave tile 4Mx8N (0.375 LDS frag-reads/MFMA — min LDS traffic structure).
//  - embedded stream-copy of inactive block inact[i] (128 KB), one 16B
//    chunk/thread loaded and one NT-stored per K-step, 4 rolling reg slots.
//    Barriers are lgkm-only, so copy vmem + weight prefetch stay in flight
//    across all 36 steps (R6's failure was vmcnt(0) drains; R11 removed them).
// A: 18x18 px x 64ch bf16 LDS, XOR-swizzled, two channel halves.
// B: ldsB ping-pong, write-one-ahead from regs, ONE lgkm-barrier per K-step.
__global__ __launch_bounds__(256, 2) void main_kernel(
    const float* __restrict__ x, const __bf16* __restrict__ wprep,
    const float* __restrict__ scale, const float* __restrict__ shift,
    const int* __restrict__ active, const int* __restrict__ inact,
    float* __restrict__ y) {
  __shared__ unsigned char ldsA[324 * 128];   // 18*18 px x 64ch bf16 = 41472 B
  __shared__ unsigned char ldsB[2][8192];     // ping-pong 32k x 128cout bf16

  const int tid = threadIdx.x;
  const int lane = tid & 63;
  const int wid = tid >> 6;

  const int aid = active[blockIdx.x];
  const int bn = aid >> 8, by = (aid >> 4) & 15, bx = aid & 15;
  const int h0 = by * 16, w0 = bx * 16;
  const float* xb = x + (size_t)bn * (H_ * W_ * C_);

  // paired inactive block for the embedded copy (512 active = 512 inactive)
  const int cid = inact[blockIdx.x];
  const size_t cbase4 =
      ((((size_t)(cid >> 8) * H_ + ((cid >> 4) & 15) * 16) * W_ + (cid & 15) * 16) * C_) >> 2;
  const f32x4* __restrict__ xs = (const f32x4*)x;
  f32x4* __restrict__ ys = (f32x4*)y;
  f32x4 cbuf[4];                              // chunk c lives in slot c&3
  auto cidx = [&](int c) -> size_t {          // 32 chunks x 256 thr x 16 B = 128 KB
    int lin = (c << 8) + tid;
    return cbase4 + (size_t)(lin >> 9) * (W_ * C_ / 4) + (lin & 511);
  };

  f32x4 acc[4][8];
  f32x4 zero = {0.f, 0.f, 0.f, 0.f};
#pragma unroll
  for (int i = 0; i < 4; ++i)
#pragma unroll
    for (int jj = 0; jj < 8; ++jj) acc[i][jj] = zero;

  const uint4* wp4 = (const uint4*)wprep;
  uint4 t0, t1;
  auto load_t = [&](int u) {                  // weight tile for flat K-step u
    int ks = u % 18, h = u / 18;
    int tile = ((ks >> 1) << 2) + (h << 1) + (ks & 1);
    t0 = wp4[tile * 512 + tid];
    t1 = wp4[tile * 512 + 256 + tid];
  };
  auto stage = [&](int half) {                // 18x18 px x 64ch -> bf16 LDS, XOR-swizzled
    for (int u = tid; u < 324 * 8; u += 256) {
      int s = u >> 3, c8 = u & 7;
      int iy = s / 18, ix = s - iy * 18;
      int hs = h0 + iy, wsp = w0 + ix;
      float4 f0 = make_float4(0.f, 0.f, 0.f, 0.f), f1 = f0;
      if (hs < H_ && wsp < W_) {
        const float* p = xb + (size_t)(hs * W_ + wsp) * C_ + half * 64 + c8 * 8;
        f0 = *(const float4*)p;
        f1 = *(const float4*)(p + 4);
      }
      bf16x8 v;
      v[0] = (__bf16)f0.x; v[1] = (__bf16)f0.y; v[2] = (__bf16)f0.z; v[3] = (__bf16)f0.w;
      v[4] = (__bf16)f1.x; v[5] = (__bf16)f1.y; v[6] = (__bf16)f1.z; v[7] = (__bf16)f1.w;
      int lin = s * 128 + c8 * 16;
      *(bf16x8*)(&ldsA[lin ^ ((s & 7) << 4)]) = v;
    }
  };

  // prologue: copy chunks 0,1 issued FIRST (deep HBM prefetch), then weights+A
  cbuf[0] = xs[cidx(0)];
  cbuf[1] = xs[cidx(1)];
  load_t(0);
  stage(0);
  ((uint4*)ldsB[0])[tid] = t0;
  ((uint4*)ldsB[0])[256 + tid] = t1;
  load_t(1);
  LGKM_BARRIER();

  const int koff = (lane >> 4) * 16;          // 16B k-chunk within 32 channels
  const int colb = (lane & 15) * 16;
  const int krow = (lane >> 4) * 2048;

#pragma unroll 4                              // 36 = 9 x 4, no remainder: cbuf/cur static
  for (int u = 0; u < 36; ++u) {
    const int cur = u & 1;

    // embedded copy: store chunk u (loaded at u-2 / prologue), load chunk u+2.
    // Slots: chunk c -> cbuf[c&3]; store@u reads u&3, load@u writes (u+2)&3.
    if (u < 32) __builtin_nontemporal_store(cbuf[u & 3], &ys[cidx(u)]);
    if (u < 30) cbuf[(u + 2) & 3] = xs[cidx(u + 2)];

    if (u < 35) {
      ((uint4*)ldsB[cur ^ 1])[tid] = t0;      // tile u+1 (loose vmcnt: copies unaffected)
      ((uint4*)ldsB[cur ^ 1])[256 + tid] = t1;
      if (u < 34) load_t(u + 2);              // rides across barriers
    }
    int ks = u % 18;
    int tap = ks >> 1, kch = ks & 1;
    int dyv = tap / 3, dxv = tap - dyv * 3;

    bf16x8 a[4];
#pragma unroll
    for (int mi = 0; mi < 4; ++mi) {
      int srow = (wid * 4 + mi + dyv) * 18 + dxv + (lane & 15);
      int lin = srow * 128 + kch * 64 + koff;
      a[mi] = *(const bf16x8*)(&ldsA[lin ^ ((srow & 7) << 4)]);
    }
    bf16x8 bfr[8];
#pragma unroll
    for (int nb = 0; nb < 8; ++nb)
      bfr[nb] = *(const bf16x8*)(&ldsB[cur][krow + nb * 256 + colb]);
#pragma unroll
    for (int mi = 0; mi < 4; ++mi)
#pragma unroll
      for (int nb = 0; nb < 8; ++nb)
        acc[mi][nb] = __builtin_amdgcn_mfma_f32_16x16x32_bf16(a[mi], bfr[nb], acc[mi][nb], 0, 0, 0);

    LGKM_BARRIER();                           // LDS visibility only; vmcnt NOT drained

    if (u == 17) {                            // re-stage ldsA with channel half 1
      stage(1);
      LGKM_BARRIER();
    }
  }

  // epilogue: BN + ReLU + scatter. D frag: col=lane&15, row=(lane>>4)*4+reg
  const int colc = lane & 15;
  float sc[8], sh[8];
#pragma unroll
  for (int nb = 0; nb < 8; ++nb) {
    sc[nb] = scale[nb * 16 + colc];
    sh[nb] = shift[nb * 16 + colc];
  }
  float* yb = y + (((size_t)bn * H_ + h0) * W_ + w0) * C_;
#pragma unroll
  for (int mi = 0; mi < 4; ++mi) {
    int oy = wid * 4 + mi;
#pragma unroll
    for (int r = 0; r < 4; ++r) {
      int ox = (lane >> 4) * 4 + r;
      float* yr = yb + ((size_t)oy * W_ + ox) * C_;
#pragma unroll
      for (int nb = 0; nb < 8; ++nb) {
        float v = acc[mi][nb][r] * sc[nb] + sh[nb];
        __builtin_nontemporal_store(fmaxf(v, 0.f), &yr[nb * 16 + colc]);
      }
    }
  }
}

extern "C" void kernel_launch(void* const* d_in, const int* in_sizes, int n_in,
                              void* d_out, int out_size, void* d_ws, size_t ws_size,
                              hipStream_t stream) {
  const float* x     = (const float*)d_in[0];
  const float* w     = (const float*)d_in[1];
  const float* b     = (const float*)d_in[2];
  const float* gamma = (const float*)d_in[3];
  const float* beta  = (const float*)d_in[4];
  const float* mean  = (const float*)d_in[5];
  const float* var   = (const float*)d_in[6];
  const int*   act   = (const int*)d_in[7];
  float* y = (float*)d_out;
  char* ws = (char*)d_ws;
  __bf16* wprep = (__bf16*)ws;
  float* scale = (float*)(ws + SCALE_OFF);
  float* shift = (float*)(ws + SHIFT_OFF);
  int* inact = (int*)(ws + INACT_OFF);

  prep_kernel<<<dim3(577), dim3(256), 0, stream>>>(w, b, gamma, beta, mean, var, act,
                                                   wprep, scale, shift, inact);
  main_kernel<<<dim3(NACT), dim3(256), 0, stream>>>(x, wprep, scale, shift, act, inact, y);
}